// Round 2
// baseline (432.468 us; speedup 1.0000x reference)
//
#include <hip/hip_runtime.h>

typedef __attribute__((ext_vector_type(4))) float  f4;
typedef __attribute__((ext_vector_type(8))) short  bf16x8;
typedef __attribute__((ext_vector_type(4))) float  f32x4;
typedef __attribute__((ext_vector_type(4))) unsigned short us4;
typedef __attribute__((ext_vector_type(2))) unsigned int u32x2;

#define BATCH 64
#define FEAT 2048
#define NC_C 112
#define TE 1024          // 2*E
#define EE 512
#define NCLS 345
#define NCLSP 352
#define KHEAD 57344      // C*E

__device__ __forceinline__ unsigned short f2bf(float f) {
    unsigned u = __float_as_uint(f);
    unsigned r = (u + 0x7FFFu + ((u >> 16) & 1u)) >> 16;
    return (unsigned short)r;
}
__device__ __forceinline__ float bf2f(unsigned short h) {
    return __uint_as_float(((unsigned)h) << 16);
}
// packed f32x2 -> bf16x2 (RNE), low half = a, high half = b
__device__ __forceinline__ unsigned cvtpk(float a, float b) {
    unsigned r;
    asm("v_cvt_pk_bf16_f32 %0, %1, %2" : "=v"(r) : "v"(a), "v"(b));
    return r;
}

// ---------------------------------------------------------------------------
// K1: embeddings = x @ W_emb[c] + b_emb   (per c), bf16 MFMA, 64x128 tiles
// grid: 896 = 112 c * 8 n-tiles, block 256 (4 waves, 2x2 over 64x128)
// 2-deep register prefetch pipeline: set issued at step s is written to LDS
// at step s+2 -> ~2 phases of latency cover; compiler emits counted vmcnt(6).
// ---------------------------------------------------------------------------
__global__ __launch_bounds__(256) void k_emb(
    const float* __restrict__ x, const float* __restrict__ W_emb,
    const float* __restrict__ b_emb, unsigned short* __restrict__ emb_bf)
{
    __shared__ __align__(16) unsigned short Alds[64 * 40];   // [row][k] stride 40
    __shared__ __align__(16) unsigned short Blds[128 * 40];  // [n][k] swizzled

    const int tid = threadIdx.x;
    const int c  = blockIdx.x >> 3;
    const int n0 = (blockIdx.x & 7) * 128;
    const float* __restrict__ Wc = W_emb + (size_t)c * (FEAT * TE);

    const int w = tid >> 6, l = tid & 63;
    const int mbase = (w & 1) * 32, nbase = (w >> 1) * 64;

    const int a_row = tid >> 3;           // 0..31 (+32 second row)
    const int a_k4  = (tid & 7) * 4;
    const int b_kp  = tid >> 4;           // 0..15
    const int b_n4  = (tid & 15) * 4;

    const float* __restrict__ axp = x + (size_t)a_row * FEAT + a_k4;
    const float* __restrict__ bpp = Wc + (size_t)(2 * b_kp) * TE + n0 + b_n4;

    unsigned short* __restrict__ aw0 = &Alds[a_row * 40 + a_k4];
    unsigned short* __restrict__ aw1 = &Alds[(a_row + 32) * 40 + a_k4];
    const int koct = b_kp >> 2, klo = (2 * b_kp) & 7;

    auto ke_load = [&](f4& A0, f4& A1, f4& B0, f4& B1, f4& B2, f4& B3, int kstep) {
        const float* ax_ = axp + kstep * 32;
        A0 = *(const f4*)ax_;
        A1 = *(const f4*)(ax_ + 32 * FEAT);
        const float* bp_ = bpp + (size_t)kstep * 32 * TE;
        B0 = *(const f4*)bp_;         B1 = *(const f4*)(bp_ + TE);
        B2 = *(const f4*)(bp_ + 64);  B3 = *(const f4*)(bp_ + TE + 64);
    };
    auto ke_write = [&](const f4& A0, const f4& A1, const f4& B0, const f4& B1,
                        const f4& B2, const f4& B3) {
        u32x2 v0, v1;
        v0[0] = cvtpk(A0[0], A0[1]); v0[1] = cvtpk(A0[2], A0[3]);
        v1[0] = cvtpk(A1[0], A1[1]); v1[1] = cvtpk(A1[2], A1[3]);
        *(u32x2*)aw0 = v0;
        *(u32x2*)aw1 = v1;
#pragma unroll
        for (int i = 0; i < 4; ++i) {
            int n = b_n4 + i;
            *(unsigned*)&Blds[n * 40 + (((koct ^ ((n >> 2) & 3)) << 3) | klo)] =
                cvtpk(B0[i], B1[i]);
            n += 64;
            *(unsigned*)&Blds[n * 40 + (((koct ^ ((n >> 2) & 3)) << 3) | klo)] =
                cvtpk(B2[i], B3[i]);
        }
    };

    f32x4 acc[2][4];
#pragma unroll
    for (int i = 0; i < 2; ++i)
#pragma unroll
        for (int j = 0; j < 4; ++j) acc[i][j] = (f32x4){0.f, 0.f, 0.f, 0.f};

    auto ke_mfma = [&]() {
        bf16x8 af[2], bfr[4];
#pragma unroll
        for (int si = 0; si < 2; ++si)
            af[si] = *(const bf16x8*)&Alds[(mbase + si * 16 + (l & 15)) * 40 + (l >> 4) * 8];
#pragma unroll
        for (int nf = 0; nf < 4; ++nf) {
            int n = nbase + nf * 16 + (l & 15);
            bfr[nf] = *(const bf16x8*)&Blds[n * 40 + (((l >> 4) ^ ((n >> 2) & 3)) << 3)];
        }
#pragma unroll
        for (int si = 0; si < 2; ++si)
#pragma unroll
            for (int nf = 0; nf < 4; ++nf)
                acc[si][nf] = __builtin_amdgcn_mfma_f32_16x16x32_bf16(
                    af[si], bfr[nf], acc[si][nf], 0, 0, 0);
    };

    f4 aA0, aA1, bA0, bA1, bA2, bA3;   // set A
    f4 aB0, aB1, bB0, bB1, bB2, bB3;   // set B
    ke_load(aA0, aA1, bA0, bA1, bA2, bA3, 0);
    ke_load(aB0, aB1, bB0, bB1, bB2, bB3, 1);

    for (int s = 0; s < 64; s += 2) {
        __syncthreads();
        ke_write(aA0, aA1, bA0, bA1, bA2, bA3);
        __syncthreads();
        if (s < 62) ke_load(aA0, aA1, bA0, bA1, bA2, bA3, s + 2);
        ke_mfma();

        __syncthreads();
        ke_write(aB0, aB1, bB0, bB1, bB2, bB3);
        __syncthreads();
        if (s < 61) ke_load(aB0, aB1, bB0, bB1, bB2, bB3, s + 3);
        ke_mfma();
    }

    // epilogue: + b_emb, store bf16 to ws  (emb layout [b][c][e])
#pragma unroll
    for (int si = 0; si < 2; ++si)
#pragma unroll
        for (int nf = 0; nf < 4; ++nf) {
            const int nl = nbase + nf * 16 + (l & 15);
            const int ng = n0 + nl;
            const float bias = b_emb[c * TE + ng];
#pragma unroll
            for (int r = 0; r < 4; ++r) {
                const int bb = mbase + si * 16 + (l >> 4) * 4 + r;
                const float v = acc[si][nf][r] + bias;
                emb_bf[((size_t)bb * NC_C + c) * TE + ng] = f2bf(v);
            }
        }
}

// ---------------------------------------------------------------------------
// K2: p_int = sigmoid(emb . W_pint + b_pint); mixed = p*pos + (1-p)*neg
// one wave per (b,c); grid 1792 * 256
// ---------------------------------------------------------------------------
__global__ __launch_bounds__(256) void k_mix(
    const unsigned short* __restrict__ emb_bf, const float* __restrict__ W_pint,
    const float* __restrict__ b_pint, float* __restrict__ flat_out,
    float* __restrict__ p_out)
{
    const int tid = threadIdx.x;
    const int l = tid & 63, w = tid >> 6;
    const int pidx = blockIdx.x * 4 + w;           // 0..7167
    const int b = pidx / NC_C, c = pidx - b * NC_C;

    const unsigned short* __restrict__ row = emb_bf + ((size_t)b * NC_C + c) * TE;
    const float* __restrict__ wp = W_pint + c * TE;

    float vals[16];
    float dot = 0.f;
#pragma unroll
    for (int i = 0; i < 4; ++i) {
        const int e = 4 * l + 256 * i;
        us4 u = *(const us4*)&row[e];
        f4  wv = *(const f4*)&wp[e];
#pragma unroll
        for (int j = 0; j < 4; ++j) {
            float f = bf2f(u[j]);
            vals[i * 4 + j] = f;
            dot += f * wv[j];
        }
    }
#pragma unroll
    for (int m = 32; m >= 1; m >>= 1) dot += __shfl_xor(dot, m);
    const float logit = dot + b_pint[c];
    const float p = 1.f / (1.f + __expf(-logit));
    if (l == 0) p_out[b * NC_C + c] = p;

    float* __restrict__ fo = flat_out + (size_t)b * KHEAD + c * EE;
#pragma unroll
    for (int i = 0; i < 2; ++i) {
        const int e = 4 * l + 256 * i;
        f4 m;
#pragma unroll
        for (int j = 0; j < 4; ++j)
            m[j] = p * vals[i * 4 + j] + (1.f - p) * vals[(i + 2) * 4 + j];
        *(f4*)&fo[e] = m;
    }
}

// ---------------------------------------------------------------------------
// K3: partial = flat @ W_head for this block's K-slice -> pbuf[blk][64][352]
// atomic-free split-K; nsteps*32 K per block
// ---------------------------------------------------------------------------
__global__ __launch_bounds__(256) void k_head(
    const float* __restrict__ flat, const float* __restrict__ W_head,
    float* __restrict__ pbuf, int nsteps)
{
    __shared__ __align__(16) unsigned short Blds[NCLSP * 40];  // [n][k] swizzled

    const int tid = threadIdx.x;
    const int w = tid >> 6, l = tid & 63;
    const int k0 = blockIdx.x * (nsteps * 32);

    f32x4 acc[22];
#pragma unroll
    for (int i = 0; i < 22; ++i) acc[i] = (f32x4){0.f, 0.f, 0.f, 0.f};

    for (int s = 0; s < nsteps; ++s) {
        const int kb = k0 + s * 32;
        __syncthreads();
        for (int idx = tid; idx < 32 * NCLSP; idx += 256) {
            const int k = idx / NCLSP;
            const int n = idx - k * NCLSP;
            const float v = (n < NCLS) ? W_head[(size_t)(kb + k) * NCLS + n] : 0.f;
            Blds[n * 40 + ((((k >> 3) ^ ((n >> 2) & 3)) << 3) | (k & 7))] = f2bf(v);
        }
        __syncthreads();

        // A-frag direct from global f32 (L2/L3-hot), convert in-register
        const float* __restrict__ ap =
            flat + (size_t)(w * 16 + (l & 15)) * KHEAD + kb + (l >> 4) * 8;
        f4 af0 = *(const f4*)ap;
        f4 af1 = *(const f4*)(ap + 4);
        bf16x8 a;
        unsigned p0 = cvtpk(af0[0], af0[1]), p1 = cvtpk(af0[2], af0[3]);
        unsigned p2 = cvtpk(af1[0], af1[1]), p3 = cvtpk(af1[2], af1[3]);
        a[0] = (short)(p0 & 0xFFFF); a[1] = (short)(p0 >> 16);
        a[2] = (short)(p1 & 0xFFFF); a[3] = (short)(p1 >> 16);
        a[4] = (short)(p2 & 0xFFFF); a[5] = (short)(p2 >> 16);
        a[6] = (short)(p3 & 0xFFFF); a[7] = (short)(p3 >> 16);

#pragma unroll
        for (int nf = 0; nf < 22; ++nf) {
            const int n = nf * 16 + (l & 15);
            bf16x8 bfr = *(const bf16x8*)&Blds[n * 40 + (((l >> 4) ^ ((n >> 2) & 3)) << 3)];
            acc[nf] = __builtin_amdgcn_mfma_f32_16x16x32_bf16(a, bfr, acc[nf], 0, 0, 0);
        }
    }

    float* __restrict__ pb = pbuf + (size_t)blockIdx.x * (64 * NCLSP);
#pragma unroll
    for (int nf = 0; nf < 22; ++nf) {
        const int n = nf * 16 + (l & 15);
#pragma unroll
        for (int r = 0; r < 4; ++r) {
            const int row = w * 16 + (l >> 4) * 4 + r;
            pb[row * NCLSP + n] = acc[nf][r];
        }
    }
}

// ---------------------------------------------------------------------------
// K4: final = b_head + sum_p partial[p]   (deterministic reduce)
// ---------------------------------------------------------------------------
__global__ __launch_bounds__(256) void k_reduce(
    const float* __restrict__ pbuf, const float* __restrict__ b_head,
    float* __restrict__ final_out, int nb)
{
    const int i = blockIdx.x * 256 + threadIdx.x;
    if (i >= BATCH * NCLS) return;
    const int m = i / NCLS, n = i - m * NCLS;
    float s = b_head[n];
    for (int p = 0; p < nb; ++p)
        s += pbuf[((size_t)p * 64 + m) * NCLSP + n];
    final_out[i] = s;
}

extern "C" void kernel_launch(void* const* d_in, const int* in_sizes, int n_in,
                              void* d_out, int out_size, void* d_ws, size_t ws_size,
                              hipStream_t stream) {
    const float* x      = (const float*)d_in[0];
    const float* W_emb  = (const float*)d_in[1];
    const float* b_emb  = (const float*)d_in[2];
    const float* W_pint = (const float*)d_in[3];
    const float* b_pint = (const float*)d_in[4];
    const float* W_head = (const float*)d_in[5];
    const float* b_head = (const float*)d_in[6];

    float* out       = (float*)d_out;
    float* final_out = out;                                   // 64*345
    float* flat      = out + BATCH * NCLS;                    // 64*57344
    float* p_out     = out + BATCH * NCLS + BATCH * KHEAD;    // 64*112

    unsigned short* emb_bf = (unsigned short*)d_ws;           // 64*112*1024 bf16
    // partials overlay the emb region (emb is dead after k_mix; stream-ordered)
    float* pbuf = (float*)d_ws;

    int NB, nsteps;
    const size_t need224 = (size_t)224 * 64 * NCLSP * sizeof(float);  // 20.2 MB
    if (ws_size >= need224) { NB = 224; nsteps = 8; }
    else                    { NB = 128; nsteps = 14; }

    k_emb<<<NC_C * 8, 256, 0, stream>>>(x, W_emb, b_emb, emb_bf);
    k_mix<<<(BATCH * NC_C) / 4, 256, 0, stream>>>(emb_bf, W_pint, b_pint, flat, p_out);
    k_head<<<NB, 256, 0, stream>>>(flat, W_head, pbuf, nsteps);
    k_reduce<<<(BATCH * NCLS + 255) / 256, 256, 0, stream>>>(pbuf, b_head, final_out, NB);
}